// Round 2
// baseline (3871.950 us; speedup 1.0000x reference)
//
#include <hip/hip_runtime.h>
#include <math.h>

#define NTH 256

struct F4 { float x, y, z, w; };
__device__ __forceinline__ F4 ld4(const float* p) { return *reinterpret_cast<const F4*>(p); }
__device__ __forceinline__ void st4(float* p, F4 v) { *reinterpret_cast<F4*>(p) = v; }

__host__ __device__ constexpr int pc_(int v) { int c = 0; while (v) { c += v & 1; v >>= 1; } return c; }
__host__ __device__ constexpr int gp_sign(int a, int b) {
    int s = 0; int t = a >> 1;
    while (t) { s += pc_(t & b); t >>= 1; }
    return (s & 1) ? -1 : 1;
}

// blades order [0,1,2,4,3,5,6,7]; table maps position->blade (involution)
#define BLADE(i) ((int)((0x76534210u >> ((i) * 4)) & 0xF))

__device__ __forceinline__ float gelu_tanh(float z) {
    float u = 0.7978845608028654f * (z + 0.044715f * z * z * z);
    return 0.5f * z * (1.0f + tanhf(u));
}

__global__ __launch_bounds__(NTH) void nbody_fused(
    const float* __restrict__ nodes, const float* __restrict__ edges,
    const float* __restrict__ src_mask,
    const float* __restrict__ W_in, const float* __restrict__ b_in,
    const float* __restrict__ W_gp, const float* __restrict__ b_gp,
    const float* __restrict__ Wq, const float* __restrict__ Wk,
    const float* __restrict__ Wv, const float* __restrict__ Wo,
    const float* __restrict__ ln1g, const float* __restrict__ ln1b,
    const float* __restrict__ ln2g, const float* __restrict__ ln2b,
    const float* __restrict__ W1, const float* __restrict__ b1,
    const float* __restrict__ W2, const float* __restrict__ b2,
    float* __restrict__ out)
{
    __shared__ __align__(16) float L[7680];
    float* XS   = L;            // [25][56] residual x
    float* HA   = L + 1400;     // h / attn-out / h2
    float* QB   = L + 2800;     // src stage, then q;  FFN: f-chunk low half
    float* KB   = L + 4200;     // mv stage, then k;   FFN: f-chunk high half
    float* VB   = L + 5600;     // gp stage, then v
    float* MK   = L + 7000;     // [25][25] mask
    float* MEAN = L + 7625;     // [25]
    float* RSTD = L + 7650;     // [25]
    float* FB   = L + 2800;     // [25][112] FFN chunk (aliases QB+KB)

    const int b = blockIdx.x;
    const int tid = threadIdx.x;

    // ---- P0: load src (25 tokens x 3 ch x 8) and mask ----
    for (int t = tid; t < 600; t += NTH) {
        int s = t / 24, r = t % 24;
        QB[t] = (s < 5) ? nodes[b * 120 + t] : edges[b * 480 + (s - 5) * 24 + r];
    }
    for (int t = tid; t < 625; t += NTH) MK[t] = src_mask[b * 625 + t];
    __syncthreads();

    // ---- P1: src_mv = mv_linear(src, W_in, b_in)  -> KB[s][n*8+i] ----
    for (int t = tid; t < 1400; t += NTH) {
        int s = t / 56, rem = t % 56, n = rem >> 3, i = rem & 7;
        int g = __popc(BLADE(i));   // grade of blade at position i
        float acc = (i == 0) ? b_in[n] : 0.0f;
        #pragma unroll
        for (int m = 0; m < 3; m++)
            acc += QB[s * 24 + m * 8 + i] * W_in[n * 12 + m * 4 + g];
        KB[t] = acc;
    }
    __syncthreads();

    // ---- P2: geometric product per (token, channel) -> VB ----
    for (int t = tid; t < 175; t += NTH) {
        int s = t / 7, n = t % 7;
        float m8[8], g8[8];
        #pragma unroll
        for (int i = 0; i < 8; i++) { m8[i] = KB[s * 56 + n * 8 + i]; g8[i] = 0.0f; }
        #pragma unroll
        for (int ai = 0; ai < 8; ai++) {
            const int a = BLADE(ai);
            #pragma unroll
            for (int bi = 0; bi < 8; bi++) {
                const int bb = BLADE(bi);
                const int j = BLADE(a ^ bb);      // position of blade a^b
                const int sg = gp_sign(a, bb);
                g8[j] += (sg > 0) ? (m8[ai] * m8[bi]) : (-m8[ai] * m8[bi]);
            }
        }
        #pragma unroll
        for (int j = 0; j < 8; j++) VB[s * 56 + n * 8 + j] = g8[j];
    }
    __syncthreads();

    // ---- P3: src2 = mv_linear(concat(mv,gp), W_gp, b_gp) -> XS ----
    for (int t = tid; t < 1400; t += NTH) {
        int s = t / 56, rem = t % 56, n = rem >> 3, i = rem & 7;
        int g = __popc(BLADE(i));
        float acc = (i == 0) ? b_gp[n] : 0.0f;
        #pragma unroll
        for (int m = 0; m < 7; m++)
            acc += KB[s * 56 + m * 8 + i] * W_gp[n * 56 + m * 4 + g];
        #pragma unroll
        for (int m = 0; m < 7; m++)
            acc += VB[s * 56 + m * 8 + i] * W_gp[n * 56 + (7 + m) * 4 + g];
        XS[t] = acc;
    }
    __syncthreads();

    const float rscale = 0.3779644730092272f;  // 1/sqrt(7)

    for (int l = 0; l < 4; l++) {
        const float* wq = Wq + l * 3136;
        const float* wk = Wk + l * 3136;
        const float* wv = Wv + l * 3136;
        const float* wo = Wo + l * 3136;
        const float* w1 = W1 + l * 12544;
        const float* w2 = W2 + l * 12544;
        const float* g1 = ln1g + l * 56; const float* e1 = ln1b + l * 56;
        const float* g2 = ln2g + l * 56; const float* e2 = ln2b + l * 56;
        const float* bb1 = b1 + l * 224; const float* bb2 = b2 + l * 56;

        // LN1 stats
        if (tid < 25) {
            float sum = 0.f, sq = 0.f;
            for (int d = 0; d < 56; d += 4) {
                F4 v = ld4(XS + tid * 56 + d);
                sum += v.x + v.y + v.z + v.w;
                sq  += v.x * v.x + v.y * v.y + v.z * v.z + v.w * v.w;
            }
            float mean = sum * (1.0f / 56.0f);
            float var  = sq  * (1.0f / 56.0f) - mean * mean;
            MEAN[tid] = mean; RSTD[tid] = rsqrtf(var + 1e-5f);
        }
        __syncthreads();
        for (int t = tid; t < 1400; t += NTH) {
            int s = t / 56, d = t % 56;
            HA[t] = (XS[t] - MEAN[s]) * RSTD[s] * g1[d] + e1[d];
        }
        __syncthreads();

        // ---- q,k,v fused: 210 threads, each computes a 5-row x 4-col tile ----
        if (tid < 210) {
            int mat = tid / 70, rem = tid % 70, rg = rem / 14, cq = rem % 14;
            const float* w = (mat == 0) ? wq : (mat == 1) ? wk : wv;
            float* dst = (mat == 0) ? QB : (mat == 1) ? KB : VB;
            int s0 = rg * 5, c = cq * 4;
            F4 acc[5] = {};
            for (int k = 0; k < 56; k += 4) {
                F4 w0 = ld4(w + (k + 0) * 56 + c);
                F4 w1r = ld4(w + (k + 1) * 56 + c);
                F4 w2r = ld4(w + (k + 2) * 56 + c);
                F4 w3r = ld4(w + (k + 3) * 56 + c);
                #pragma unroll
                for (int r = 0; r < 5; r++) {
                    F4 h = ld4(HA + (s0 + r) * 56 + k);
                    acc[r].x += h.x * w0.x + h.y * w1r.x + h.z * w2r.x + h.w * w3r.x;
                    acc[r].y += h.x * w0.y + h.y * w1r.y + h.z * w2r.y + h.w * w3r.y;
                    acc[r].z += h.x * w0.z + h.y * w1r.z + h.z * w2r.z + h.w * w3r.z;
                    acc[r].w += h.x * w0.w + h.y * w1r.w + h.z * w2r.w + h.w * w3r.w;
                }
            }
            float sc_ = (mat == 0) ? rscale : 1.0f;
            #pragma unroll
            for (int r = 0; r < 5; r++) {
                acc[r].x *= sc_; acc[r].y *= sc_; acc[r].z *= sc_; acc[r].w *= sc_;
                st4(dst + (s0 + r) * 56 + c, acc[r]);
            }
        }
        __syncthreads();

        // attention: one thread per (query s, head hh); writes o into HA
        if (tid < 200) {
            int s = tid >> 3, hh = tid & 7;
            int base = hh * 7;
            float qr[7];
            #pragma unroll
            for (int d = 0; d < 7; d++) qr[d] = QB[s * 56 + base + d];
            float sc[25]; float mx = -1e30f;
            #pragma unroll
            for (int kk = 0; kk < 25; kk++) {
                float dot = 0.f;
                #pragma unroll
                for (int d = 0; d < 7; d++) dot += qr[d] * KB[kk * 56 + base + d];
                dot += MK[s * 25 + kk];
                sc[kk] = dot; mx = fmaxf(mx, dot);
            }
            float ssum = 0.f;
            #pragma unroll
            for (int kk = 0; kk < 25; kk++) { float e = __expf(sc[kk] - mx); sc[kk] = e; ssum += e; }
            float inv = 1.0f / ssum;
            float acc[7];
            #pragma unroll
            for (int d = 0; d < 7; d++) acc[d] = 0.f;
            #pragma unroll
            for (int kk = 0; kk < 25; kk++) {
                float p = sc[kk];
                #pragma unroll
                for (int d = 0; d < 7; d++) acc[d] += p * VB[kk * 56 + base + d];
            }
            #pragma unroll
            for (int d = 0; d < 7; d++) HA[s * 56 + base + d] = acc[d] * inv;
        }
        __syncthreads();

        // ---- x += o @ Wo : 70 threads, 5x4 register tile each ----
        if (tid < 70) {
            int rg = tid / 14, cq = tid % 14;
            int s0 = rg * 5, c = cq * 4;
            F4 acc[5] = {};
            for (int k = 0; k < 56; k += 4) {
                F4 w0 = ld4(wo + (k + 0) * 56 + c);
                F4 w1r = ld4(wo + (k + 1) * 56 + c);
                F4 w2r = ld4(wo + (k + 2) * 56 + c);
                F4 w3r = ld4(wo + (k + 3) * 56 + c);
                #pragma unroll
                for (int r = 0; r < 5; r++) {
                    F4 h = ld4(HA + (s0 + r) * 56 + k);
                    acc[r].x += h.x * w0.x + h.y * w1r.x + h.z * w2r.x + h.w * w3r.x;
                    acc[r].y += h.x * w0.y + h.y * w1r.y + h.z * w2r.y + h.w * w3r.y;
                    acc[r].z += h.x * w0.z + h.y * w1r.z + h.z * w2r.z + h.w * w3r.z;
                    acc[r].w += h.x * w0.w + h.y * w1r.w + h.z * w2r.w + h.w * w3r.w;
                }
            }
            #pragma unroll
            for (int r = 0; r < 5; r++) {
                F4 xv = ld4(XS + (s0 + r) * 56 + c);
                xv.x += acc[r].x; xv.y += acc[r].y; xv.z += acc[r].z; xv.w += acc[r].w;
                st4(XS + (s0 + r) * 56 + c, xv);
            }
        }
        __syncthreads();

        // LN2 -> h2 in HA
        if (tid < 25) {
            float sum = 0.f, sq = 0.f;
            for (int d = 0; d < 56; d += 4) {
                F4 v = ld4(XS + tid * 56 + d);
                sum += v.x + v.y + v.z + v.w;
                sq  += v.x * v.x + v.y * v.y + v.z * v.z + v.w * v.w;
            }
            float mean = sum * (1.0f / 56.0f);
            float var  = sq  * (1.0f / 56.0f) - mean * mean;
            MEAN[tid] = mean; RSTD[tid] = rsqrtf(var + 1e-5f);
        }
        __syncthreads();
        for (int t = tid; t < 1400; t += NTH) {
            int s = t / 56, d = t % 56;
            HA[t] = (XS[t] - MEAN[s]) * RSTD[s] * g2[d] + e2[d];
        }
        __syncthreads();

        // FFN in two 112-col chunks; f-chunk aliases QB/KB
        for (int cc = 0; cc < 2; cc++) {
            // f = gelu(h2 @ W1 + b1) for cols [cc*112, cc*112+112): 140 threads, 5x4 tile
            if (tid < 140) {
                int rg = tid / 28, cq = tid % 28;
                int s0 = rg * 5;
                int col = cc * 112 + cq * 4;
                F4 acc[5] = {};
                for (int k = 0; k < 56; k += 4) {
                    F4 w0 = ld4(w1 + (k + 0) * 224 + col);
                    F4 w1r = ld4(w1 + (k + 1) * 224 + col);
                    F4 w2r = ld4(w1 + (k + 2) * 224 + col);
                    F4 w3r = ld4(w1 + (k + 3) * 224 + col);
                    #pragma unroll
                    for (int r = 0; r < 5; r++) {
                        F4 h = ld4(HA + (s0 + r) * 56 + k);
                        acc[r].x += h.x * w0.x + h.y * w1r.x + h.z * w2r.x + h.w * w3r.x;
                        acc[r].y += h.x * w0.y + h.y * w1r.y + h.z * w2r.y + h.w * w3r.y;
                        acc[r].z += h.x * w0.z + h.y * w1r.z + h.z * w2r.z + h.w * w3r.z;
                        acc[r].w += h.x * w0.w + h.y * w1r.w + h.z * w2r.w + h.w * w3r.w;
                    }
                }
                #pragma unroll
                for (int r = 0; r < 5; r++) {
                    F4 o;
                    o.x = gelu_tanh(acc[r].x + bb1[col + 0]);
                    o.y = gelu_tanh(acc[r].y + bb1[col + 1]);
                    o.z = gelu_tanh(acc[r].z + bb1[col + 2]);
                    o.w = gelu_tanh(acc[r].w + bb1[col + 3]);
                    st4(FB + (s0 + r) * 112 + cq * 4, o);
                }
            }
            __syncthreads();
            // x += f @ W2[chunk] (+ b2 on chunk 0): 70 threads, 5x4 tile, K=112
            if (tid < 70) {
                int rg = tid / 14, cq = tid % 14;
                int s0 = rg * 5, c = cq * 4;
                F4 acc[5] = {};
                for (int k = 0; k < 112; k += 4) {
                    F4 w0 = ld4(w2 + (cc * 112 + k + 0) * 56 + c);
                    F4 w1r = ld4(w2 + (cc * 112 + k + 1) * 56 + c);
                    F4 w2r = ld4(w2 + (cc * 112 + k + 2) * 56 + c);
                    F4 w3r = ld4(w2 + (cc * 112 + k + 3) * 56 + c);
                    #pragma unroll
                    for (int r = 0; r < 5; r++) {
                        F4 h = ld4(FB + (s0 + r) * 112 + k);
                        acc[r].x += h.x * w0.x + h.y * w1r.x + h.z * w2r.x + h.w * w3r.x;
                        acc[r].y += h.x * w0.y + h.y * w1r.y + h.z * w2r.y + h.w * w3r.y;
                        acc[r].z += h.x * w0.z + h.y * w1r.z + h.z * w2r.z + h.w * w3r.z;
                        acc[r].w += h.x * w0.w + h.y * w1r.w + h.z * w2r.w + h.w * w3r.w;
                    }
                }
                float bx = (cc == 0) ? bb2[c + 0] : 0.f;
                float by = (cc == 0) ? bb2[c + 1] : 0.f;
                float bz = (cc == 0) ? bb2[c + 2] : 0.f;
                float bw = (cc == 0) ? bb2[c + 3] : 0.f;
                #pragma unroll
                for (int r = 0; r < 5; r++) {
                    F4 xv = ld4(XS + (s0 + r) * 56 + c);
                    xv.x += acc[r].x + bx; xv.y += acc[r].y + by;
                    xv.z += acc[r].z + bz; xv.w += acc[r].w + bw;
                    st4(XS + (s0 + r) * 56 + c, xv);
                }
            }
            __syncthreads();
        }
    }

    // ---- output: x[:, :5, channel 1, :] -> (B*5, 8) ----
    for (int t = tid; t < 40; t += NTH) {
        int s = t >> 3, j = t & 7;
        out[(b * 5 + s) * 8 + j] = XS[s * 56 + 8 + j];
    }
}

extern "C" void kernel_launch(void* const* d_in, const int* in_sizes, int n_in,
                              void* d_out, int out_size, void* d_ws, size_t ws_size,
                              hipStream_t stream) {
    const float* nodes = (const float*)d_in[0];
    const float* edges = (const float*)d_in[1];
    const float* mask  = (const float*)d_in[2];
    const int B = in_sizes[0] / 120;   // (B*5, 3, 8)
    const float* W_in = (const float*)d_in[4];
    const float* b_in = (const float*)d_in[5];
    const float* W_gp = (const float*)d_in[6];
    const float* b_gp = (const float*)d_in[7];
    const float* Wq   = (const float*)d_in[8];
    const float* Wk   = (const float*)d_in[9];
    const float* Wv   = (const float*)d_in[10];
    const float* Wo   = (const float*)d_in[11];
    const float* ln1g = (const float*)d_in[12];
    const float* ln1b = (const float*)d_in[13];
    const float* ln2g = (const float*)d_in[14];
    const float* ln2b = (const float*)d_in[15];
    const float* W1   = (const float*)d_in[16];
    const float* b1   = (const float*)d_in[17];
    const float* W2   = (const float*)d_in[18];
    const float* b2   = (const float*)d_in[19];
    float* out = (float*)d_out;

    hipLaunchKernelGGL(nbody_fused, dim3(B), dim3(NTH), 0, stream,
                       nodes, edges, mask, W_in, b_in, W_gp, b_gp,
                       Wq, Wk, Wv, Wo, ln1g, ln1b, ln2g, ln2b,
                       W1, b1, W2, b2, out);
}

// Round 3
// 401.743 us; speedup vs baseline: 9.6379x; 9.6379x over previous
//
#include <hip/hip_runtime.h>
#include <math.h>

#define NTH 256
#define FSTR 232   // FB row stride in ushorts (bank-conflict-free for b128 reads)

typedef __attribute__((ext_vector_type(8))) short short8;
typedef __attribute__((ext_vector_type(4))) float f32x4;

__device__ __forceinline__ unsigned short f2bf(float x) {
    unsigned int u = __float_as_uint(x);
    return (unsigned short)((u + 0x7FFFu + ((u >> 16) & 1u)) >> 16);  // RNE
}

__host__ __device__ constexpr int pc_(int v) { int c = 0; while (v) { c += v & 1; v >>= 1; } return c; }
__host__ __device__ constexpr int gp_sign(int a, int b) {
    int s = 0; int t = a >> 1;
    while (t) { s += pc_(t & b); t >>= 1; }
    return (s & 1) ? -1 : 1;
}
// blades order [0,1,2,4,3,5,6,7]; table maps position->blade (involution)
#define BLADE(i) ((int)((0x76534210u >> ((i) * 4)) & 0xF))

__device__ __forceinline__ float gelu_fast(float z) {
    float u = 1.5957691216057308f * (z + 0.044715f * z * z * z);  // 2*0.79788456*(...)
    float E = __expf(u);
    return z - z / (E + 1.0f);   // = 0.5 z (1+tanh(u/2)); inf-safe
}

// ---------------- weight prep: bf16, transposed (WT[n][k]), zero-padded ----------------
// layout in ws (ushorts):
//   [0, L*16384)              : qkvo  [(l*4+mat)*64 + n]*64 + k   (n,k < 64; rscale folded into Wq)
//   [+0, L*14336)             : w1t   [(l*224 + n)*64 + k]        (n < 224, k < 64)
//   [+0, L*14336)             : w2t   [(l*64 + n)*224 + k]        (n < 64, k < 224)
__global__ void prep_weights(const float* __restrict__ Wq, const float* __restrict__ Wk,
                             const float* __restrict__ Wv, const float* __restrict__ Wo,
                             const float* __restrict__ W1, const float* __restrict__ W2,
                             unsigned short* __restrict__ ws, int L)
{
    int idx = blockIdx.x * NTH + threadIdx.x;
    int total1 = L * 16384, total2 = L * 14336, total3 = L * 14336;
    if (idx < total1) {
        int k = idx & 63, n = (idx >> 6) & 63, mat = (idx >> 12) & 3, l = idx >> 14;
        float v = 0.f;
        if (k < 56 && n < 56) {
            const float* W = (mat == 0) ? Wq : (mat == 1) ? Wk : (mat == 2) ? Wv : Wo;
            v = W[l * 3136 + k * 56 + n];
            if (mat == 0) v *= 0.3779644730092272f;  // 1/sqrt(7) folded
        }
        ws[idx] = f2bf(v);
    } else if (idx < total1 + total2) {
        int t = idx - total1;
        int k = t & 63, n = (t >> 6) % 224, l = t / 14336;
        float v = (k < 56) ? W1[l * 12544 + k * 224 + n] : 0.f;
        ws[idx] = f2bf(v);
    } else if (idx < total1 + total2 + total3) {
        int t = idx - total1 - total2;
        int k = t % 224, n = (t / 224) & 63, l = t / 14336;
        float v = (n < 56) ? W2[l * 12544 + k * 56 + n] : 0.f;
        ws[idx] = f2bf(v);
    }
}

__global__ __launch_bounds__(NTH, 4) void nbody_fused(
    const float* __restrict__ nodes, const float* __restrict__ edges,
    const float* __restrict__ src_mask,
    const float* __restrict__ W_in, const float* __restrict__ b_in,
    const float* __restrict__ W_gp, const float* __restrict__ b_gp,
    const float* __restrict__ ln1g, const float* __restrict__ ln1b,
    const float* __restrict__ ln2g, const float* __restrict__ ln2b,
    const float* __restrict__ b1, const float* __restrict__ b2,
    const unsigned short* __restrict__ ws, int L,
    float* __restrict__ out)
{
    __shared__ __align__(16) float XS[1400];            // residual [25][56] fp32
    __shared__ __align__(16) unsigned short HB[2304];   // h bf16 [32][72]; cols56-63 zero k-pad
    __shared__ __align__(16) float QKVF[4200];          // QB/KB/VB fp32 [25][56]x3; FB aliases
    __shared__ __align__(16) float MK[625];
    __shared__ float MEAN[25], RSTD[25];

    float* QB = QKVF; float* KB = QKVF + 1400; float* VB = QKVF + 2800;
    unsigned short* FB = (unsigned short*)QKVF;         // [32][FSTR] bf16

    const int b = blockIdx.x, tid = threadIdx.x;
    const int lane = tid & 63, wid = tid >> 6;
    const int nl = lane & 15, quad = lane >> 4;

    // ---- P0: load src + mask; zero HB k-pad ----
    for (int t = tid; t < 600; t += NTH) {
        int s = t / 24, r = t % 24;
        QB[t] = (s < 5) ? nodes[b * 120 + t] : edges[b * 480 + (s - 5) * 24 + r];
    }
    for (int t = tid; t < 625; t += NTH) MK[t] = src_mask[b * 625 + t];
    {   // 256 threads cover 32 rows x 8 pad cols
        int r = tid >> 3, c = 56 + (tid & 7);
        HB[r * 72 + c] = 0;
    }
    __syncthreads();

    // ---- P1: src_mv = mv_linear(src, W_in, b_in) -> KB ----
    for (int t = tid; t < 1400; t += NTH) {
        int s = t / 56, rem = t % 56, n = rem >> 3, i = rem & 7;
        int g = __popc(BLADE(i));
        float acc = (i == 0) ? b_in[n] : 0.0f;
        #pragma unroll
        for (int m = 0; m < 3; m++)
            acc += QB[s * 24 + m * 8 + i] * W_in[n * 12 + m * 4 + g];
        KB[t] = acc;
    }
    __syncthreads();

    // ---- P2: geometric product -> VB ----
    for (int t = tid; t < 175; t += NTH) {
        int s = t / 7, n = t % 7;
        float m8[8], g8[8];
        #pragma unroll
        for (int i = 0; i < 8; i++) { m8[i] = KB[s * 56 + n * 8 + i]; g8[i] = 0.0f; }
        #pragma unroll
        for (int ai = 0; ai < 8; ai++) {
            const int a = BLADE(ai);
            #pragma unroll
            for (int bi = 0; bi < 8; bi++) {
                const int bb = BLADE(bi);
                const int j = BLADE(a ^ bb);
                const int sg = gp_sign(a, bb);
                g8[j] += (sg > 0) ? (m8[ai] * m8[bi]) : (-m8[ai] * m8[bi]);
            }
        }
        #pragma unroll
        for (int j = 0; j < 8; j++) VB[s * 56 + n * 8 + j] = g8[j];
    }
    __syncthreads();

    // ---- P3: src2 -> XS ----
    for (int t = tid; t < 1400; t += NTH) {
        int s = t / 56, rem = t % 56, n = rem >> 3, i = rem & 7;
        int g = __popc(BLADE(i));
        float acc = (i == 0) ? b_gp[n] : 0.0f;
        #pragma unroll
        for (int m = 0; m < 7; m++)
            acc += KB[s * 56 + m * 8 + i] * W_gp[n * 56 + m * 4 + g];
        #pragma unroll
        for (int m = 0; m < 7; m++)
            acc += VB[s * 56 + m * 8 + i] * W_gp[n * 56 + (7 + m) * 4 + g];
        XS[t] = acc;
    }
    __syncthreads();

    const unsigned short* w1t_all = ws + (size_t)L * 16384;
    const unsigned short* w2t_all = w1t_all + (size_t)L * 14336;

    for (int l = 0; l < L; l++) {
        const float* g1 = ln1g + l * 56; const float* e1 = ln1b + l * 56;
        const float* g2 = ln2g + l * 56; const float* e2 = ln2b + l * 56;

        // LN1 stats
        if (tid < 25) {
            float sum = 0.f, sq = 0.f;
            for (int d = 0; d < 56; d++) { float v = XS[tid * 56 + d]; sum += v; sq += v * v; }
            float mean = sum * (1.0f / 56.0f);
            float var = sq * (1.0f / 56.0f) - mean * mean;
            MEAN[tid] = mean; RSTD[tid] = rsqrtf(var + 1e-5f);
        }
        __syncthreads();
        for (int t = tid; t < 1400; t += NTH) {
            int s = t / 56, d = t % 56;
            HB[s * 72 + d] = f2bf((XS[t] - MEAN[s]) * RSTD[s] * g1[d] + e1[d]);
        }
        __syncthreads();

        // ---- QKV via MFMA: wave w handles n-tile w of each of q,k,v ----
        {
            short8 a[2][2];
            #pragma unroll
            for (int mt = 0; mt < 2; mt++)
                #pragma unroll
                for (int ks = 0; ks < 2; ks++)
                    a[mt][ks] = *(const short8*)(HB + (mt * 16 + nl) * 72 + ks * 32 + quad * 8);
            int col = wid * 16 + nl;
            #pragma unroll
            for (int mat = 0; mat < 3; mat++) {
                const unsigned short* bp = ws + (((size_t)(l * 4 + mat)) << 12) + (((size_t)col) << 6) + quad * 8;
                short8 b0 = *(const short8*)(bp);
                short8 b1f = *(const short8*)(bp + 32);
                f32x4 acc0 = {0, 0, 0, 0}, acc1 = {0, 0, 0, 0};
                acc0 = __builtin_amdgcn_mfma_f32_16x16x32_bf16(a[0][0], b0, acc0, 0, 0, 0);
                acc0 = __builtin_amdgcn_mfma_f32_16x16x32_bf16(a[0][1], b1f, acc0, 0, 0, 0);
                acc1 = __builtin_amdgcn_mfma_f32_16x16x32_bf16(a[1][0], b0, acc1, 0, 0, 0);
                acc1 = __builtin_amdgcn_mfma_f32_16x16x32_bf16(a[1][1], b1f, acc1, 0, 0, 0);
                float* dst = (mat == 0) ? QB : (mat == 1) ? KB : VB;
                if (col < 56) {
                    #pragma unroll
                    for (int r = 0; r < 4; r++) {
                        int row0 = quad * 4 + r;
                        dst[row0 * 56 + col] = acc0[r];
                        int row1 = 16 + row0;
                        if (row1 < 25) dst[row1 * 56 + col] = acc1[r];
                    }
                }
            }
        }
        __syncthreads();

        // ---- attention: one thread per (query s, head hh); writes o -> HB bf16 ----
        if (tid < 200) {
            int s = tid >> 3, hh = tid & 7;
            int base = hh * 7;
            float qr[7];
            #pragma unroll
            for (int d = 0; d < 7; d++) qr[d] = QB[s * 56 + base + d];
            float sc[25]; float mx = -1e30f;
            #pragma unroll
            for (int kk = 0; kk < 25; kk++) {
                float dot = 0.f;
                #pragma unroll
                for (int d = 0; d < 7; d++) dot += qr[d] * KB[kk * 56 + base + d];
                dot += MK[s * 25 + kk];
                sc[kk] = dot; mx = fmaxf(mx, dot);
            }
            float ssum = 0.f;
            #pragma unroll
            for (int kk = 0; kk < 25; kk++) { float e = __expf(sc[kk] - mx); sc[kk] = e; ssum += e; }
            float inv = 1.0f / ssum;
            float acc[7];
            #pragma unroll
            for (int d = 0; d < 7; d++) acc[d] = 0.f;
            #pragma unroll
            for (int kk = 0; kk < 25; kk++) {
                float p = sc[kk];
                #pragma unroll
                for (int d = 0; d < 7; d++) acc[d] += p * VB[kk * 56 + base + d];
            }
            #pragma unroll
            for (int d = 0; d < 7; d++) HB[s * 72 + base + d] = f2bf(acc[d] * inv);
        }
        __syncthreads();

        // ---- x += o @ Wo : wave w = n-tile w ----
        {
            short8 a[2][2];
            #pragma unroll
            for (int mt = 0; mt < 2; mt++)
                #pragma unroll
                for (int ks = 0; ks < 2; ks++)
                    a[mt][ks] = *(const short8*)(HB + (mt * 16 + nl) * 72 + ks * 32 + quad * 8);
            int col = wid * 16 + nl;
            const unsigned short* bp = ws + (((size_t)(l * 4 + 3)) << 12) + (((size_t)col) << 6) + quad * 8;
            short8 b0 = *(const short8*)(bp);
            short8 b1f = *(const short8*)(bp + 32);
            f32x4 acc0 = {0, 0, 0, 0}, acc1 = {0, 0, 0, 0};
            acc0 = __builtin_amdgcn_mfma_f32_16x16x32_bf16(a[0][0], b0, acc0, 0, 0, 0);
            acc0 = __builtin_amdgcn_mfma_f32_16x16x32_bf16(a[0][1], b1f, acc0, 0, 0, 0);
            acc1 = __builtin_amdgcn_mfma_f32_16x16x32_bf16(a[1][0], b0, acc1, 0, 0, 0);
            acc1 = __builtin_amdgcn_mfma_f32_16x16x32_bf16(a[1][1], b1f, acc1, 0, 0, 0);
            if (col < 56) {
                #pragma unroll
                for (int r = 0; r < 4; r++) {
                    int row0 = quad * 4 + r;
                    XS[row0 * 56 + col] += acc0[r];
                    int row1 = 16 + row0;
                    if (row1 < 25) XS[row1 * 56 + col] += acc1[r];
                }
            }
        }
        __syncthreads();

        // LN2
        if (tid < 25) {
            float sum = 0.f, sq = 0.f;
            for (int d = 0; d < 56; d++) { float v = XS[tid * 56 + d]; sum += v; sq += v * v; }
            float mean = sum * (1.0f / 56.0f);
            float var = sq * (1.0f / 56.0f) - mean * mean;
            MEAN[tid] = mean; RSTD[tid] = rsqrtf(var + 1e-5f);
        }
        __syncthreads();
        for (int t = tid; t < 1400; t += NTH) {
            int s = t / 56, d = t % 56;
            HB[s * 72 + d] = f2bf((XS[t] - MEAN[s]) * RSTD[s] * g2[d] + e2[d]);
        }
        __syncthreads();

        // ---- FFN1: f = gelu(h @ W1 + b1) -> FB bf16 [32][FSTR]; 14 n-tiles over 4 waves ----
        {
            short8 a[2][2];
            #pragma unroll
            for (int mt = 0; mt < 2; mt++)
                #pragma unroll
                for (int ks = 0; ks < 2; ks++)
                    a[mt][ks] = *(const short8*)(HB + (mt * 16 + nl) * 72 + ks * 32 + quad * 8);
            for (int u = wid; u < 14; u += 4) {
                int col = u * 16 + nl;
                const unsigned short* bp = w1t_all + (((size_t)(l * 224 + col)) << 6) + quad * 8;
                short8 b0 = *(const short8*)(bp);
                short8 b1f = *(const short8*)(bp + 32);
                f32x4 acc0 = {0, 0, 0, 0}, acc1 = {0, 0, 0, 0};
                acc0 = __builtin_amdgcn_mfma_f32_16x16x32_bf16(a[0][0], b0, acc0, 0, 0, 0);
                acc0 = __builtin_amdgcn_mfma_f32_16x16x32_bf16(a[0][1], b1f, acc0, 0, 0, 0);
                acc1 = __builtin_amdgcn_mfma_f32_16x16x32_bf16(a[1][0], b0, acc1, 0, 0, 0);
                acc1 = __builtin_amdgcn_mfma_f32_16x16x32_bf16(a[1][1], b1f, acc1, 0, 0, 0);
                float bias = b1[l * 224 + col];
                #pragma unroll
                for (int r = 0; r < 4; r++) {
                    int row0 = quad * 4 + r;
                    FB[row0 * FSTR + col] = f2bf(gelu_fast(acc0[r] + bias));
                    int row1 = 16 + row0;
                    if (row1 < 25) FB[row1 * FSTR + col] = f2bf(gelu_fast(acc1[r] + bias));
                }
            }
        }
        __syncthreads();

        // ---- FFN2: x += f @ W2 + b2 : wave w = n-tile w, K=224 (7 k-steps) ----
        {
            int col = wid * 16 + nl;
            const unsigned short* bp0 = w2t_all + ((size_t)(l * 64 + col)) * 224 + quad * 8;
            f32x4 acc0 = {0, 0, 0, 0}, acc1 = {0, 0, 0, 0};
            #pragma unroll
            for (int ks = 0; ks < 7; ks++) {
                short8 bfrag = *(const short8*)(bp0 + ks * 32);
                short8 a0 = *(const short8*)(FB + nl * FSTR + ks * 32 + quad * 8);
                short8 a1 = *(const short8*)(FB + (16 + nl) * FSTR + ks * 32 + quad * 8);
                acc0 = __builtin_amdgcn_mfma_f32_16x16x32_bf16(a0, bfrag, acc0, 0, 0, 0);
                acc1 = __builtin_amdgcn_mfma_f32_16x16x32_bf16(a1, bfrag, acc1, 0, 0, 0);
            }
            if (col < 56) {
                float bias = b2[l * 56 + col];
                #pragma unroll
                for (int r = 0; r < 4; r++) {
                    int row0 = quad * 4 + r;
                    XS[row0 * 56 + col] += acc0[r] + bias;
                    int row1 = 16 + row0;
                    if (row1 < 25) XS[row1 * 56 + col] += acc1[r] + bias;
                }
            }
        }
        __syncthreads();
    }

    // ---- output: x[:, :5, channel 1, :] ----
    for (int t = tid; t < 40; t += NTH) {
        int s = t >> 3, j = t & 7;
        out[(b * 5 + s) * 8 + j] = XS[s * 56 + 8 + j];
    }
}

extern "C" void kernel_launch(void* const* d_in, const int* in_sizes, int n_in,
                              void* d_out, int out_size, void* d_ws, size_t ws_size,
                              hipStream_t stream) {
    const float* nodes = (const float*)d_in[0];
    const float* edges = (const float*)d_in[1];
    const float* mask  = (const float*)d_in[2];
    const int B = in_sizes[0] / 120;       // (B*5, 3, 8)
    const float* W_in = (const float*)d_in[4];
    const float* b_in = (const float*)d_in[5];
    const float* W_gp = (const float*)d_in[6];
    const float* b_gp = (const float*)d_in[7];
    const float* Wq   = (const float*)d_in[8];
    const float* Wk   = (const float*)d_in[9];
    const float* Wv   = (const float*)d_in[10];
    const float* Wo   = (const float*)d_in[11];
    const float* ln1g = (const float*)d_in[12];
    const float* ln1b = (const float*)d_in[13];
    const float* ln2g = (const float*)d_in[14];
    const float* ln2b = (const float*)d_in[15];
    const float* W1   = (const float*)d_in[16];
    const float* b1   = (const float*)d_in[17];
    const float* W2   = (const float*)d_in[18];
    const float* b2   = (const float*)d_in[19];
    float* out = (float*)d_out;
    const int L = in_sizes[8] / 3136;      // Wq is (L, 56, 56)

    unsigned short* ws16 = (unsigned short*)d_ws;
    int prep_total = L * (16384 + 14336 + 14336);
    hipLaunchKernelGGL(prep_weights, dim3((prep_total + NTH - 1) / NTH), dim3(NTH), 0, stream,
                       Wq, Wk, Wv, Wo, W1, W2, ws16, L);

    hipLaunchKernelGGL(nbody_fused, dim3(B), dim3(NTH), 0, stream,
                       nodes, edges, mask, W_in, b_in, W_gp, b_gp,
                       ln1g, ln1b, ln2g, ln2b, b1, b2, ws16, L, out);
}

// Round 4
// 394.880 us; speedup vs baseline: 9.8054x; 1.0174x over previous
//
#include <hip/hip_runtime.h>
#include <math.h>

#define NTH 256
#define XSTR 57    // XS row stride (floats) — breaks 4-way epilogue bank conflicts
#define QSTR 57    // QB/KB/VB row stride (floats)
#define FSTR 232   // FB row stride in ushorts

typedef __attribute__((ext_vector_type(8))) short short8;
typedef __attribute__((ext_vector_type(4))) float f32x4;

__device__ __forceinline__ unsigned short f2bf(float x) {
    unsigned int u = __float_as_uint(x);
    return (unsigned short)((u + 0x7FFFu + ((u >> 16) & 1u)) >> 16);  // RNE
}

__host__ __device__ constexpr int pc_(int v) { int c = 0; while (v) { c += v & 1; v >>= 1; } return c; }
__host__ __device__ constexpr int gp_sign(int a, int b) {
    int s = 0; int t = a >> 1;
    while (t) { s += pc_(t & b); t >>= 1; }
    return (s & 1) ? -1 : 1;
}
// blades order [0,1,2,4,3,5,6,7]; table maps position->blade (involution)
#define BLADE(i) ((int)((0x76534210u >> ((i) * 4)) & 0xF))

__device__ __forceinline__ float gelu_fast(float z) {
    float u = 1.5957691216057308f * (z + 0.044715f * z * z * z);
    float E = __expf(u);
    return z - z / (E + 1.0f);   // inf-safe tanh-gelu
}

// ---------------- weight prep: bf16, transposed (WT[n][k]), zero-padded ----------------
__global__ void prep_weights(const float* __restrict__ Wq, const float* __restrict__ Wk,
                             const float* __restrict__ Wv, const float* __restrict__ Wo,
                             const float* __restrict__ W1, const float* __restrict__ W2,
                             unsigned short* __restrict__ ws, int L)
{
    int idx = blockIdx.x * NTH + threadIdx.x;
    int total1 = L * 16384, total2 = L * 14336, total3 = L * 14336;
    if (idx < total1) {
        int k = idx & 63, n = (idx >> 6) & 63, mat = (idx >> 12) & 3, l = idx >> 14;
        float v = 0.f;
        if (k < 56 && n < 56) {
            const float* W = (mat == 0) ? Wq : (mat == 1) ? Wk : (mat == 2) ? Wv : Wo;
            v = W[l * 3136 + k * 56 + n];
            if (mat == 0) v *= 0.3779644730092272f;  // 1/sqrt(7) folded
        }
        ws[idx] = f2bf(v);
    } else if (idx < total1 + total2) {
        int t = idx - total1;
        int k = t & 63, n = (t >> 6) % 224, l = t / 14336;
        float v = (k < 56) ? W1[l * 12544 + k * 224 + n] : 0.f;
        ws[idx] = f2bf(v);
    } else if (idx < total1 + total2 + total3) {
        int t = idx - total1 - total2;
        int k = t % 224, n = (t / 224) & 63, l = t / 14336;
        float v = (n < 56) ? W2[l * 12544 + k * 56 + n] : 0.f;
        ws[idx] = f2bf(v);
    }
}

__global__ __launch_bounds__(NTH, 4) void nbody_fused(
    const float* __restrict__ nodes, const float* __restrict__ edges,
    const float* __restrict__ src_mask,
    const float* __restrict__ W_in, const float* __restrict__ b_in,
    const float* __restrict__ W_gp, const float* __restrict__ b_gp,
    const float* __restrict__ ln1g, const float* __restrict__ ln1b,
    const float* __restrict__ ln2g, const float* __restrict__ ln2b,
    const float* __restrict__ b1, const float* __restrict__ b2,
    const unsigned short* __restrict__ ws, int L,
    float* __restrict__ out)
{
    __shared__ __align__(16) float XS[25 * XSTR];       // residual fp32, padded stride
    __shared__ __align__(16) unsigned short HB[2304];   // h bf16 [32][72]; cols56-63 zero
    __shared__ __align__(16) float QKVF[3 * 25 * QSTR]; // QB/KB/VB fp32; FB aliases
    __shared__ __align__(16) float MK[625];
    __shared__ float MEAN[25], RSTD[25];

    float* QB = QKVF; float* KB = QKVF + 25 * QSTR; float* VB = QKVF + 50 * QSTR;
    unsigned short* FB = (unsigned short*)QKVF;         // [32][FSTR] bf16

    const int b = blockIdx.x, tid = threadIdx.x;
    const int lane = tid & 63, wid = tid >> 6;
    const int nl = lane & 15, quad = lane >> 4;

    // ---- P0: load src + mask; zero HB k-pad ----
    for (int t = tid; t < 600; t += NTH) {
        int s = t / 24, r = t % 24;
        QB[t] = (s < 5) ? nodes[b * 120 + t] : edges[b * 480 + (s - 5) * 24 + r];
    }
    for (int t = tid; t < 625; t += NTH) MK[t] = src_mask[b * 625 + t];
    {
        int r = tid >> 3, c = 56 + (tid & 7);
        HB[r * 72 + c] = 0;
    }
    __syncthreads();

    // ---- P1: src_mv -> KB ----
    for (int t = tid; t < 1400; t += NTH) {
        int s = t / 56, rem = t % 56, n = rem >> 3, i = rem & 7;
        int g = __popc(BLADE(i));
        float acc = (i == 0) ? b_in[n] : 0.0f;
        #pragma unroll
        for (int m = 0; m < 3; m++)
            acc += QB[s * 24 + m * 8 + i] * W_in[n * 12 + m * 4 + g];
        KB[s * QSTR + rem] = acc;
    }
    __syncthreads();

    // ---- P2: geometric product -> VB ----
    for (int t = tid; t < 175; t += NTH) {
        int s = t / 7, n = t % 7;
        float m8[8], g8[8];
        #pragma unroll
        for (int i = 0; i < 8; i++) { m8[i] = KB[s * QSTR + n * 8 + i]; g8[i] = 0.0f; }
        #pragma unroll
        for (int ai = 0; ai < 8; ai++) {
            const int a = BLADE(ai);
            #pragma unroll
            for (int bi = 0; bi < 8; bi++) {
                const int bb = BLADE(bi);
                const int j = BLADE(a ^ bb);
                const int sg = gp_sign(a, bb);
                g8[j] += (sg > 0) ? (m8[ai] * m8[bi]) : (-m8[ai] * m8[bi]);
            }
        }
        #pragma unroll
        for (int j = 0; j < 8; j++) VB[s * QSTR + n * 8 + j] = g8[j];
    }
    __syncthreads();

    // ---- P3: src2 -> XS ----
    for (int t = tid; t < 1400; t += NTH) {
        int s = t / 56, rem = t % 56, n = rem >> 3, i = rem & 7;
        int g = __popc(BLADE(i));
        float acc = (i == 0) ? b_gp[n] : 0.0f;
        #pragma unroll
        for (int m = 0; m < 7; m++)
            acc += KB[s * QSTR + m * 8 + i] * W_gp[n * 56 + m * 4 + g];
        #pragma unroll
        for (int m = 0; m < 7; m++)
            acc += VB[s * QSTR + m * 8 + i] * W_gp[n * 56 + (7 + m) * 4 + g];
        XS[s * XSTR + rem] = acc;
    }
    __syncthreads();

    const unsigned short* w1t_all = ws + (size_t)L * 16384;
    const unsigned short* w2t_all = w1t_all + (size_t)L * 14336;

    for (int l = 0; l < L; l++) {
        const float* g1 = ln1g + l * 56; const float* e1 = ln1b + l * 56;
        const float* g2 = ln2g + l * 56; const float* e2 = ln2b + l * 56;

        // LN1 stats: 8 lanes per token, shfl-xor reduce
        if (tid < 200) {
            int s = tid >> 3, p = tid & 7;
            const float* xp = XS + s * XSTR + p * 7;
            float sum = 0.f, sq = 0.f;
            #pragma unroll
            for (int j = 0; j < 7; j++) { float v = xp[j]; sum += v; sq += v * v; }
            #pragma unroll
            for (int off = 1; off < 8; off <<= 1) {
                sum += __shfl_xor(sum, off, 64);
                sq  += __shfl_xor(sq,  off, 64);
            }
            if (p == 0) {
                float mean = sum * (1.0f / 56.0f);
                float var  = sq  * (1.0f / 56.0f) - mean * mean;
                MEAN[s] = mean; RSTD[s] = rsqrtf(var + 1e-5f);
            }
        }
        __syncthreads();
        for (int t = tid; t < 700; t += NTH) {
            int s = t / 28, d = (t - s * 28) * 2;
            float m = MEAN[s], rs = RSTD[s];
            float x0 = XS[s * XSTR + d], x1 = XS[s * XSTR + d + 1];
            float y0 = (x0 - m) * rs * g1[d] + e1[d];
            float y1 = (x1 - m) * rs * g1[d + 1] + e1[d + 1];
            *(unsigned int*)(HB + s * 72 + d) =
                (unsigned int)f2bf(y0) | ((unsigned int)f2bf(y1) << 16);
        }
        __syncthreads();

        // ---- QKV via MFMA ----
        {
            short8 a[2][2];
            #pragma unroll
            for (int mt = 0; mt < 2; mt++)
                #pragma unroll
                for (int ks = 0; ks < 2; ks++)
                    a[mt][ks] = *(const short8*)(HB + (mt * 16 + nl) * 72 + ks * 32 + quad * 8);
            int col = wid * 16 + nl;
            #pragma unroll
            for (int mat = 0; mat < 3; mat++) {
                const unsigned short* bp = ws + (((size_t)(l * 4 + mat)) << 12) + (((size_t)col) << 6) + quad * 8;
                short8 b0 = *(const short8*)(bp);
                short8 b1f = *(const short8*)(bp + 32);
                f32x4 acc0 = {0, 0, 0, 0}, acc1 = {0, 0, 0, 0};
                acc0 = __builtin_amdgcn_mfma_f32_16x16x32_bf16(a[0][0], b0, acc0, 0, 0, 0);
                acc0 = __builtin_amdgcn_mfma_f32_16x16x32_bf16(a[0][1], b1f, acc0, 0, 0, 0);
                acc1 = __builtin_amdgcn_mfma_f32_16x16x32_bf16(a[1][0], b0, acc1, 0, 0, 0);
                acc1 = __builtin_amdgcn_mfma_f32_16x16x32_bf16(a[1][1], b1f, acc1, 0, 0, 0);
                float* dst = (mat == 0) ? QB : (mat == 1) ? KB : VB;
                if (col < 56) {
                    #pragma unroll
                    for (int r = 0; r < 4; r++) {
                        int row0 = quad * 4 + r;
                        dst[row0 * QSTR + col] = acc0[r];
                        int row1 = 16 + row0;
                        if (row1 < 25) dst[row1 * QSTR + col] = acc1[r];
                    }
                }
            }
        }
        __syncthreads();

        // ---- attention: thread per (query s, head hh) -> HB bf16 ----
        if (tid < 200) {
            int s = tid >> 3, hh = tid & 7;
            int base = hh * 7;
            float qr[7];
            #pragma unroll
            for (int d = 0; d < 7; d++) qr[d] = QB[s * QSTR + base + d];
            float sc[25]; float mx = -1e30f;
            #pragma unroll
            for (int kk = 0; kk < 25; kk++) {
                float dot = 0.f;
                #pragma unroll
                for (int d = 0; d < 7; d++) dot += qr[d] * KB[kk * QSTR + base + d];
                dot += MK[s * 25 + kk];
                sc[kk] = dot; mx = fmaxf(mx, dot);
            }
            float ssum = 0.f;
            #pragma unroll
            for (int kk = 0; kk < 25; kk++) { float e = __expf(sc[kk] - mx); sc[kk] = e; ssum += e; }
            float inv = 1.0f / ssum;
            float acc[7];
            #pragma unroll
            for (int d = 0; d < 7; d++) acc[d] = 0.f;
            #pragma unroll
            for (int kk = 0; kk < 25; kk++) {
                float p = sc[kk];
                #pragma unroll
                for (int d = 0; d < 7; d++) acc[d] += p * VB[kk * QSTR + base + d];
            }
            #pragma unroll
            for (int d = 0; d < 7; d++) HB[s * 72 + base + d] = f2bf(acc[d] * inv);
        }
        __syncthreads();

        // ---- x += o @ Wo ----
        {
            short8 a[2][2];
            #pragma unroll
            for (int mt = 0; mt < 2; mt++)
                #pragma unroll
                for (int ks = 0; ks < 2; ks++)
                    a[mt][ks] = *(const short8*)(HB + (mt * 16 + nl) * 72 + ks * 32 + quad * 8);
            int col = wid * 16 + nl;
            const unsigned short* bp = ws + (((size_t)(l * 4 + 3)) << 12) + (((size_t)col) << 6) + quad * 8;
            short8 b0 = *(const short8*)(bp);
            short8 b1f = *(const short8*)(bp + 32);
            f32x4 acc0 = {0, 0, 0, 0}, acc1 = {0, 0, 0, 0};
            acc0 = __builtin_amdgcn_mfma_f32_16x16x32_bf16(a[0][0], b0, acc0, 0, 0, 0);
            acc0 = __builtin_amdgcn_mfma_f32_16x16x32_bf16(a[0][1], b1f, acc0, 0, 0, 0);
            acc1 = __builtin_amdgcn_mfma_f32_16x16x32_bf16(a[1][0], b0, acc1, 0, 0, 0);
            acc1 = __builtin_amdgcn_mfma_f32_16x16x32_bf16(a[1][1], b1f, acc1, 0, 0, 0);
            if (col < 56) {
                #pragma unroll
                for (int r = 0; r < 4; r++) {
                    int row0 = quad * 4 + r;
                    XS[row0 * XSTR + col] += acc0[r];
                    int row1 = 16 + row0;
                    if (row1 < 25) XS[row1 * XSTR + col] += acc1[r];
                }
            }
        }
        __syncthreads();

        // LN2 stats
        if (tid < 200) {
            int s = tid >> 3, p = tid & 7;
            const float* xp = XS + s * XSTR + p * 7;
            float sum = 0.f, sq = 0.f;
            #pragma unroll
            for (int j = 0; j < 7; j++) { float v = xp[j]; sum += v; sq += v * v; }
            #pragma unroll
            for (int off = 1; off < 8; off <<= 1) {
                sum += __shfl_xor(sum, off, 64);
                sq  += __shfl_xor(sq,  off, 64);
            }
            if (p == 0) {
                float mean = sum * (1.0f / 56.0f);
                float var  = sq  * (1.0f / 56.0f) - mean * mean;
                MEAN[s] = mean; RSTD[s] = rsqrtf(var + 1e-5f);
            }
        }
        __syncthreads();
        for (int t = tid; t < 700; t += NTH) {
            int s = t / 28, d = (t - s * 28) * 2;
            float m = MEAN[s], rs = RSTD[s];
            float x0 = XS[s * XSTR + d], x1 = XS[s * XSTR + d + 1];
            float y0 = (x0 - m) * rs * g2[d] + e2[d];
            float y1 = (x1 - m) * rs * g2[d + 1] + e2[d + 1];
            *(unsigned int*)(HB + s * 72 + d) =
                (unsigned int)f2bf(y0) | ((unsigned int)f2bf(y1) << 16);
        }
        __syncthreads();

        // ---- FFN1: f = gelu(h @ W1 + b1) -> FB bf16 ----
        {
            short8 a[2][2];
            #pragma unroll
            for (int mt = 0; mt < 2; mt++)
                #pragma unroll
                for (int ks = 0; ks < 2; ks++)
                    a[mt][ks] = *(const short8*)(HB + (mt * 16 + nl) * 72 + ks * 32 + quad * 8);
            for (int u = wid; u < 14; u += 4) {
                int col = u * 16 + nl;
                const unsigned short* bp = w1t_all + (((size_t)(l * 224 + col)) << 6) + quad * 8;
                short8 b0 = *(const short8*)(bp);
                short8 b1f = *(const short8*)(bp + 32);
                f32x4 acc0 = {0, 0, 0, 0}, acc1 = {0, 0, 0, 0};
                acc0 = __builtin_amdgcn_mfma_f32_16x16x32_bf16(a[0][0], b0, acc0, 0, 0, 0);
                acc0 = __builtin_amdgcn_mfma_f32_16x16x32_bf16(a[0][1], b1f, acc0, 0, 0, 0);
                acc1 = __builtin_amdgcn_mfma_f32_16x16x32_bf16(a[1][0], b0, acc1, 0, 0, 0);
                acc1 = __builtin_amdgcn_mfma_f32_16x16x32_bf16(a[1][1], b1f, acc1, 0, 0, 0);
                float bias = b1[l * 224 + col];
                #pragma unroll
                for (int r = 0; r < 4; r++) {
                    int row0 = quad * 4 + r;
                    FB[row0 * FSTR + col] = f2bf(gelu_fast(acc0[r] + bias));
                    int row1 = 16 + row0;
                    if (row1 < 25) FB[row1 * FSTR + col] = f2bf(gelu_fast(acc1[r] + bias));
                }
            }
        }
        __syncthreads();

        // ---- FFN2: x += f @ W2 + b2 (K=224, 7 k-steps) ----
        {
            int col = wid * 16 + nl;
            const unsigned short* bp0 = w2t_all + ((size_t)(l * 64 + col)) * 224 + quad * 8;
            f32x4 acc0 = {0, 0, 0, 0}, acc1 = {0, 0, 0, 0};
            #pragma unroll
            for (int ks = 0; ks < 7; ks++) {
                short8 bfrag = *(const short8*)(bp0 + ks * 32);
                short8 a0 = *(const short8*)(FB + nl * FSTR + ks * 32 + quad * 8);
                short8 a1 = *(const short8*)(FB + (16 + nl) * FSTR + ks * 32 + quad * 8);
                acc0 = __builtin_amdgcn_mfma_f32_16x16x32_bf16(a0, bfrag, acc0, 0, 0, 0);
                acc1 = __builtin_amdgcn_mfma_f32_16x16x32_bf16(a1, bfrag, acc1, 0, 0, 0);
            }
            if (col < 56) {
                float bias = b2[l * 56 + col];
                #pragma unroll
                for (int r = 0; r < 4; r++) {
                    int row0 = quad * 4 + r;
                    XS[row0 * XSTR + col] += acc0[r] + bias;
                    int row1 = 16 + row0;
                    if (row1 < 25) XS[row1 * XSTR + col] += acc1[r] + bias;
                }
            }
        }
        __syncthreads();
    }

    // ---- output ----
    for (int t = tid; t < 40; t += NTH) {
        int s = t >> 3, j = t & 7;
        out[(b * 5 + s) * 8 + j] = XS[s * XSTR + 8 + j];
    }
}

extern "C" void kernel_launch(void* const* d_in, const int* in_sizes, int n_in,
                              void* d_out, int out_size, void* d_ws, size_t ws_size,
                              hipStream_t stream) {
    const float* nodes = (const float*)d_in[0];
    const float* edges = (const float*)d_in[1];
    const float* mask  = (const float*)d_in[2];
    const int B = in_sizes[0] / 120;
    const float* W_in = (const float*)d_in[4];
    const float* b_in = (const float*)d_in[5];
    const float* W_gp = (const float*)d_in[6];
    const float* b_gp = (const float*)d_in[7];
    const float* Wq   = (const float*)d_in[8];
    const float* Wk   = (const float*)d_in[9];
    const float* Wv   = (const float*)d_in[10];
    const float* Wo   = (const float*)d_in[11];
    const float* ln1g = (const float*)d_in[12];
    const float* ln1b = (const float*)d_in[13];
    const float* ln2g = (const float*)d_in[14];
    const float* ln2b = (const float*)d_in[15];
    const float* W1   = (const float*)d_in[16];
    const float* b1   = (const float*)d_in[17];
    const float* W2   = (const float*)d_in[18];
    const float* b2   = (const float*)d_in[19];
    float* out = (float*)d_out;
    const int L = in_sizes[8] / 3136;

    unsigned short* ws16 = (unsigned short*)d_ws;
    int prep_total = L * (16384 + 14336 + 14336);
    hipLaunchKernelGGL(prep_weights, dim3((prep_total + NTH - 1) / NTH), dim3(NTH), 0, stream,
                       Wq, Wk, Wv, Wo, W1, W2, ws16, L);

    hipLaunchKernelGGL(nbody_fused, dim3(B), dim3(NTH), 0, stream,
                       nodes, edges, mask, W_in, b_in, W_gp, b_gp,
                       ln1g, ln1b, ln2g, ln2b, b1, b2, ws16, L, out);
}